// Round 3
// baseline (660.398 us; speedup 1.0000x reference)
//
#include <hip/hip_runtime.h>

#define NN 100000
#define EE 1600000
#define GG 1000
#define BN_EPS 1e-5f

// ---------- segment-max via monotonic uint encoding ----------
__device__ __forceinline__ unsigned encf(float f){
  unsigned u = __float_as_uint(f);
  return (u & 0x80000000u) ? ~u : (u | 0x80000000u);
}
__device__ __forceinline__ float dec0(unsigned e){
  unsigned u = (e & 0x80000000u) ? (e & 0x7fffffffu) : ~e;
  float f = __uint_as_float(u);
  return isfinite(f) ? f : 0.0f;   // init-0 sentinel decodes to NaN -> 0 (empty segment)
}

// ---------- degree ----------
__global__ void k_deg(const int* __restrict__ ei, const int* __restrict__ ew,
                      float* __restrict__ deg){
  int e = blockIdx.x*256 + threadIdx.x;
  if (e < EE && ew[e] == 1) atomicAdd(&deg[ei[EE + e]], 1.0f);
}
__global__ void k_dinv(float* __restrict__ deg){
  int i = blockIdx.x*256 + threadIdx.x;
  if (i < NN) deg[i] = rsqrtf(deg[i] + 1.0f);  // +1 self loop
}

// ---------- GEMM1: Y1 = x@W1 + b1, accumulate column sum/sumsq ----------
__global__ __launch_bounds__(256) void k_gemm1(const float* __restrict__ x,
    const float* __restrict__ W1, const float* __restrict__ b1,
    float* __restrict__ Y1, float* __restrict__ stats){
  __shared__ float xs[32*132];     // 32 rows x 128, padded
  __shared__ float Ws[128*32];
  __shared__ float red[64];
  const int tid = threadIdx.x;
  for (int j = tid; j < 1024; j += 256) ((float4*)Ws)[j] = ((const float4*)W1)[j];
  const int r = tid >> 3, cg = tid & 7;
  const float4 bv = ((const float4*)b1)[cg];
  float s0=0,s1=0,s2=0,s3=0,q0=0,q1=0,q2=0,q3=0;
  for (int tile = blockIdx.x; tile < 3125; tile += gridDim.x){
    __syncthreads();
    for (int j = tid; j < 1024; j += 256){
      int rr = j >> 5, kk = j & 31;
      *(float4*)&xs[rr*132 + kk*4] = ((const float4*)x)[(size_t)tile*1024 + j];
    }
    __syncthreads();
    float a0=bv.x, a1=bv.y, a2=bv.z, a3=bv.w;
    const float* xr = &xs[r*132];
    const float* wc = &Ws[cg*4];
    #pragma unroll 8
    for (int k = 0; k < 128; k++){
      float xv = xr[k];
      float4 w = *(const float4*)&wc[k*32];
      a0 += xv*w.x; a1 += xv*w.y; a2 += xv*w.z; a3 += xv*w.w;
    }
    float4 o; o.x=a0; o.y=a1; o.z=a2; o.w=a3;
    ((float4*)Y1)[(size_t)(tile*32 + r)*8 + cg] = o;
    s0+=a0; s1+=a1; s2+=a2; s3+=a3;
    q0+=a0*a0; q1+=a1*a1; q2+=a2*a2; q3+=a3*a3;
  }
  __syncthreads();
  if (tid < 64) red[tid] = 0.f;
  __syncthreads();
  atomicAdd(&red[cg*4+0], s0); atomicAdd(&red[cg*4+1], s1);
  atomicAdd(&red[cg*4+2], s2); atomicAdd(&red[cg*4+3], s3);
  atomicAdd(&red[32+cg*4+0], q0); atomicAdd(&red[32+cg*4+1], q1);
  atomicAdd(&red[32+cg*4+2], q2); atomicAdd(&red[32+cg*4+3], q3);
  __syncthreads();
  if (tid < 64) atomicAdd(&stats[tid], red[tid]);
}

// ---------- BN finalize: scale/shift from sums ----------
__global__ void k_stats(float* __restrict__ stats, const float* __restrict__ gamma,
                        const float* __restrict__ beta, int base){
  int c = threadIdx.x;  // 32 threads
  float mean = stats[base + c] * (1.0f/NN);
  float var  = stats[base + 32 + c] * (1.0f/NN) - mean*mean;
  float sc = gamma[c] * rsqrtf(fmaxf(var, 0.0f) + BN_EPS);
  stats[base + 64 + c] = sc;
  stats[base + 96 + c] = beta[c] - mean*sc;
}

// ---------- MLP2: Y2 = relu(bn1(Y1))@W2 + b2, accumulate stats2 ----------
__global__ __launch_bounds__(256) void k_mlp2(const float* __restrict__ Y1,
    const float* __restrict__ W2, const float* __restrict__ b2,
    float* __restrict__ stats, float* __restrict__ Y2){
  __shared__ float hs[32*36];
  __shared__ float Ws[32*32];
  __shared__ float red[64];
  const int tid = threadIdx.x;
  ((float4*)Ws)[tid] = ((const float4*)W2)[tid];
  const int r = tid >> 3, cg = tid & 7;
  const float4 bv = ((const float4*)b2)[cg];
  const float4 sc = ((const float4*)(stats + 64))[cg];
  const float4 sh = ((const float4*)(stats + 96))[cg];
  float s0=0,s1=0,s2=0,s3=0,q0=0,q1=0,q2=0,q3=0;
  for (int tile = blockIdx.x; tile < 3125; tile += gridDim.x){
    __syncthreads();
    {
      float4 v = ((const float4*)Y1)[(size_t)tile*256 + tid];
      v.x = fmaxf(fmaf(v.x, sc.x, sh.x), 0.f);
      v.y = fmaxf(fmaf(v.y, sc.y, sh.y), 0.f);
      v.z = fmaxf(fmaf(v.z, sc.z, sh.z), 0.f);
      v.w = fmaxf(fmaf(v.w, sc.w, sh.w), 0.f);
      *(float4*)&hs[r*36 + cg*4] = v;
    }
    __syncthreads();
    float a0=bv.x, a1=bv.y, a2=bv.z, a3=bv.w;
    const float* hr = &hs[r*36];
    const float* wc = &Ws[cg*4];
    #pragma unroll
    for (int k = 0; k < 32; k++){
      float h = hr[k];
      float4 w = *(const float4*)&wc[k*32];
      a0 += h*w.x; a1 += h*w.y; a2 += h*w.z; a3 += h*w.w;
    }
    float4 o; o.x=a0; o.y=a1; o.z=a2; o.w=a3;
    ((float4*)Y2)[(size_t)(tile*32 + r)*8 + cg] = o;
    s0+=a0; s1+=a1; s2+=a2; s3+=a3;
    q0+=a0*a0; q1+=a1*a1; q2+=a2*a2; q3+=a3*a3;
  }
  __syncthreads();
  if (tid < 64) red[tid] = 0.f;
  __syncthreads();
  atomicAdd(&red[cg*4+0], s0); atomicAdd(&red[cg*4+1], s1);
  atomicAdd(&red[cg*4+2], s2); atomicAdd(&red[cg*4+3], s3);
  atomicAdd(&red[32+cg*4+0], q0); atomicAdd(&red[32+cg*4+1], q1);
  atomicAdd(&red[32+cg*4+2], q2); atomicAdd(&red[32+cg*4+3], q3);
  __syncthreads();
  if (tid < 64) atomicAdd(&stats[128 + tid], red[tid]);
}

// ---------- layer0: h1 = relu(bn2(Y2)); Pool0 <- max(h1@Wl0+bl0);
//            Hg1 = h1@Wg1; AGG1 = Hg1*dinv^2 (self loop) ----------
__global__ __launch_bounds__(256) void k_layer0(const float* __restrict__ Y2,
    const float* __restrict__ stats, const float* __restrict__ Wg1,
    const float* __restrict__ Wl0, const float* __restrict__ bl0,
    const float* __restrict__ dinv, const int* __restrict__ batch,
    float* __restrict__ Hg1, float* __restrict__ AGG1, unsigned* __restrict__ Pool0){
  __shared__ float hs[32*36];
  __shared__ float Wg[32*64];
  __shared__ float Wl[320];
  __shared__ float bl[10];
  const int tid = threadIdx.x;
  ((float4*)Wg)[tid]       = ((const float4*)Wg1)[tid];
  ((float4*)Wg)[tid + 256] = ((const float4*)Wg1)[tid + 256];
  for (int j = tid; j < 320; j += 256) Wl[j] = Wl0[j];   // FIX: full 320-entry fill
  if (tid < 10)  bl[tid] = bl0[tid];
  {
    const int rr = tid >> 3, kk = tid & 7;
    const float4 sc = ((const float4*)(stats + 192))[kk];
    const float4 sh = ((const float4*)(stats + 224))[kk];
    float4 v = ((const float4*)Y2)[(size_t)blockIdx.x*256 + tid];
    v.x = fmaxf(fmaf(v.x, sc.x, sh.x), 0.f);
    v.y = fmaxf(fmaf(v.y, sc.y, sh.y), 0.f);
    v.z = fmaxf(fmaf(v.z, sc.z, sh.z), 0.f);
    v.w = fmaxf(fmaf(v.w, sc.w, sh.w), 0.f);
    *(float4*)&hs[rr*36 + kk*4] = v;
  }
  __syncthreads();
  const int w = tid >> 6, f = tid & 63;
  for (int i = 0; i < 8; i++){
    const int r = w*8 + i;
    const int row = blockIdx.x*32 + r;
    const float* hr = &hs[r*36];
    float acc = 0.f;
    #pragma unroll
    for (int k = 0; k < 32; k++) acc += hr[k]*Wg[k*64 + f];
    const float dv = dinv[row];
    Hg1[(size_t)row*64 + f]  = acc;
    AGG1[(size_t)row*64 + f] = acc*dv*dv;
    if (f < 10){
      float p = bl[f];
      #pragma unroll
      for (int k = 0; k < 32; k++) p += hr[k]*Wl[k*10 + f];
      atomicMax(&Pool0[batch[row]*10 + f], encf(p));
    }
  }
}

// ---------- edge scatter: AGG[col] += H[row]*w*dinv[row]*dinv[col] ----------
__global__ __launch_bounds__(256) void k_edge(const int* __restrict__ ei,
    const int* __restrict__ ew, const float* __restrict__ dinv,
    const float* __restrict__ H, float* __restrict__ AGG){
  const int e = blockIdx.x*4 + (threadIdx.x >> 6);
  if (ew[e] != 1) return;
  const int f = threadIdx.x & 63;
  const int r = ei[e], c = ei[EE + e];
  const float nrm = dinv[r]*dinv[c];
  atomicAdd(&AGG[(size_t)c*64 + f], H[(size_t)r*64 + f]*nrm);
}

// ---------- layer1: h2 = AGG1+bg1; Pool1 <- max(h2);
//            Hg2 = h2@Wg2; AGG2 = Hg2*dinv^2 ----------
__global__ __launch_bounds__(256) void k_layer1(const float* __restrict__ AGG1,
    const float* __restrict__ bg1, const float* __restrict__ Wg2,
    const float* __restrict__ dinv, const int* __restrict__ batch,
    float* __restrict__ Hg2, float* __restrict__ AGG2, unsigned* __restrict__ Pool1){
  __shared__ float as[32*68];
  __shared__ float Wg[64*64];
  const int tid = threadIdx.x;
  #pragma unroll
  for (int j = 0; j < 4; j++) ((float4*)Wg)[tid + j*256] = ((const float4*)Wg2)[tid + j*256];
  #pragma unroll
  for (int j = 0; j < 2; j++){
    int idx = tid + j*256;
    int rr = idx >> 4, kk = idx & 15;
    float4 v  = ((const float4*)AGG1)[(size_t)blockIdx.x*512 + idx];
    float4 bg = ((const float4*)bg1)[kk];
    v.x += bg.x; v.y += bg.y; v.z += bg.z; v.w += bg.w;
    *(float4*)&as[rr*68 + kk*4] = v;   // as holds h2 = agg + bg1
  }
  __syncthreads();
  const int w = tid >> 6, f = tid & 63;
  for (int i = 0; i < 8; i++){
    const int r = w*8 + i;
    const int row = blockIdx.x*32 + r;
    const float* ar = &as[r*68];
    atomicMax(&Pool1[batch[row]*64 + f], encf(ar[f]));
    float acc = 0.f;
    #pragma unroll
    for (int k = 0; k < 64; k++) acc += ar[k]*Wg[k*64 + f];
    const float dv = dinv[row];
    Hg2[(size_t)row*64 + f]  = acc;
    AGG2[(size_t)row*64 + f] = acc*dv*dv;
  }
}

// ---------- pool of layer2: h3 = AGG2 + bg2 ----------
__global__ void k_pool2(const float* __restrict__ AGG2,
    const float* __restrict__ bg2, const int* __restrict__ batch,
    unsigned* __restrict__ Pool2){
  const int t = blockIdx.x*256 + threadIdx.x;
  const int i = t >> 6, f = t & 63;
  float h = AGG2[(size_t)i*64 + f] + bg2[f];
  atomicMax(&Pool2[batch[i]*64 + f], encf(h));
}

// ---------- final: out = P0 + P1@Wl1+bl1 + P2@Wl2+bl2 ----------
__global__ __launch_bounds__(256) void k_final(const unsigned* __restrict__ P0,
    const unsigned* __restrict__ P1, const unsigned* __restrict__ P2,
    const float* __restrict__ Wl1, const float* __restrict__ bl1,
    const float* __restrict__ Wl2, const float* __restrict__ bl2,
    float* __restrict__ out){
  const int t = blockIdx.x*256 + threadIdx.x;
  const int g = t >> 4, c = t & 15;
  if (g >= GG || c >= 10) return;
  float acc = dec0(P0[g*10 + c]) + bl1[c] + bl2[c];
  for (int f = 0; f < 64; f++){
    acc += dec0(P1[g*64 + f]) * Wl1[f*10 + c];
    acc += dec0(P2[g*64 + f]) * Wl2[f*10 + c];
  }
  out[g*10 + c] = acc;
}

extern "C" void kernel_launch(void* const* d_in, const int* in_sizes, int n_in,
                              void* d_out, int out_size, void* d_ws, size_t ws_size,
                              hipStream_t stream){
  const float* x   = (const float*)d_in[0];
  const int*   ei  = (const int*)d_in[1];
  const int*   ew  = (const int*)d_in[2];
  const int*   bat = (const int*)d_in[3];
  const float* W1  = (const float*)d_in[5],  *b1  = (const float*)d_in[6];
  const float* g1  = (const float*)d_in[7],  *bt1 = (const float*)d_in[8];
  const float* W2  = (const float*)d_in[9],  *b2  = (const float*)d_in[10];
  const float* g2  = (const float*)d_in[11], *bt2 = (const float*)d_in[12];
  const float* Wl0 = (const float*)d_in[13], *bl0 = (const float*)d_in[14];
  const float* Wg1 = (const float*)d_in[15], *bg1 = (const float*)d_in[16];
  const float* Wl1 = (const float*)d_in[17], *bl1 = (const float*)d_in[18];
  const float* Wg2 = (const float*)d_in[19], *bg2 = (const float*)d_in[20];
  const float* Wl2 = (const float*)d_in[21], *bl2 = (const float*)d_in[22];

  float* ws = (float*)d_ws;
  // workspace layout (floats)
  const size_t oDeg = 0;                       // N
  const size_t oStats = NN;                    // 256
  const size_t oP0 = NN + 256;                 // G*10
  const size_t oP1 = oP0 + (size_t)GG*10;      // G*64
  const size_t oP2 = oP1 + (size_t)GG*64;      // G*64
  const size_t oA  = oP2 + (size_t)GG*64;      // N*64: Y1 | Y2, reused as Hg2
  const size_t oB  = oA + (size_t)NN*64;       // N*64: Hg1, reused as AGG2
  const size_t oC  = oB + (size_t)NN*64;       // N*64: AGG1

  float* deg   = ws + oDeg;
  float* stats = ws + oStats;
  unsigned* P0 = (unsigned*)(ws + oP0);
  unsigned* P1 = (unsigned*)(ws + oP1);
  unsigned* P2 = (unsigned*)(ws + oP2);
  float* Y1   = ws + oA;
  float* Y2   = ws + oA + (size_t)NN*32;
  float* Hg2  = ws + oA;       // reuse after Y2 consumed
  float* Hg1  = ws + oB;
  float* AGG2 = ws + oB;       // reuse after Hg1 consumed
  float* AGG1 = ws + oC;

  // zero: deg, stats, pool sentinels (enc 0 -> decodes NaN -> 0)
  (void)hipMemsetAsync(d_ws, 0, oA*sizeof(float), stream);

  k_deg  <<<(EE + 255)/256, 256, 0, stream>>>(ei, ew, deg);
  k_dinv <<<(NN + 255)/256, 256, 0, stream>>>(deg);
  k_gemm1<<<512, 256, 0, stream>>>(x, W1, b1, Y1, stats);
  k_stats<<<1, 32, 0, stream>>>(stats, g1, bt1, 0);
  k_mlp2 <<<512, 256, 0, stream>>>(Y1, W2, b2, stats, Y2);
  k_stats<<<1, 32, 0, stream>>>(stats, g2, bt2, 128);
  k_layer0<<<3125, 256, 0, stream>>>(Y2, stats, Wg1, Wl0, bl0, deg, bat, Hg1, AGG1, P0);
  k_edge <<<EE/4, 256, 0, stream>>>(ei, ew, deg, Hg1, AGG1);
  k_layer1<<<3125, 256, 0, stream>>>(AGG1, bg1, Wg2, deg, bat, Hg2, AGG2, P1);
  k_edge <<<EE/4, 256, 0, stream>>>(ei, ew, deg, Hg2, AGG2);
  k_pool2<<<(size_t)NN*64/256, 256, 0, stream>>>(AGG2, bg2, bat, P2);
  k_final<<<(GG*16 + 255)/256, 256, 0, stream>>>(P0, P1, P2, Wl1, bl1, Wl2, bl2, (float*)d_out);
}

// Round 4
// 345.710 us; speedup vs baseline: 1.9103x; 1.9103x over previous
//
#include <hip/hip_runtime.h>

#define NN 100000
#define EE 1600000
#define GG 1000
#define BN_EPS 1e-5f
#define NB1 391        // ceil(NN/256) scan blocks

// ---------- segment-max via monotonic uint encoding ----------
__device__ __forceinline__ unsigned encf(float f){
  unsigned u = __float_as_uint(f);
  return (u & 0x80000000u) ? ~u : (u | 0x80000000u);
}
__device__ __forceinline__ float dec0(unsigned e){
  unsigned u = (e & 0x80000000u) ? (e & 0x7fffffffu) : ~e;
  float f = __uint_as_float(u);
  return isfinite(f) ? f : 0.0f;   // init-0 sentinel decodes to NaN -> 0 (empty segment)
}

// ---------- CSR build: count -> scan -> finalize -> scatter ----------
__global__ void k_count(const int* __restrict__ ei, const int* __restrict__ ew,
                        int* __restrict__ cnt){
  int e = blockIdx.x*256 + threadIdx.x;
  if (e < EE && ew[e] == 1) atomicAdd(&cnt[ei[EE + e]], 1);
}

__global__ __launch_bounds__(256) void k_scan1(const int* __restrict__ cnt,
    int* __restrict__ loc, int* __restrict__ bsum){
  __shared__ int sm[256];
  const int i = blockIdx.x*256 + threadIdx.x;
  const int v = (i < NN) ? cnt[i] : 0;
  sm[threadIdx.x] = v;
  __syncthreads();
  for (int off = 1; off < 256; off <<= 1){
    int t = (threadIdx.x >= off) ? sm[threadIdx.x - off] : 0;
    __syncthreads();
    sm[threadIdx.x] += t;
    __syncthreads();
  }
  if (i < NN) loc[i] = sm[threadIdx.x] - v;     // exclusive within block
  if (threadIdx.x == 255) bsum[blockIdx.x] = sm[255];
}

__global__ __launch_bounds__(512) void k_scan2(const int* __restrict__ bsum,
    int* __restrict__ boff){
  __shared__ int sm[512];
  const int t = threadIdx.x;
  const int v = (t < NB1) ? bsum[t] : 0;
  sm[t] = v;
  __syncthreads();
  for (int off = 1; off < 512; off <<= 1){
    int x = (t >= off) ? sm[t - off] : 0;
    __syncthreads();
    sm[t] += x;
    __syncthreads();
  }
  if (t <= NB1) boff[t] = sm[t] - v;            // boff[NB1] = total
}

__global__ void k_fin(const int* __restrict__ cnt, const int* __restrict__ loc,
                      const int* __restrict__ boff, float* __restrict__ dinv,
                      int* __restrict__ rowstart, int* __restrict__ fill){
  const int i = blockIdx.x*256 + threadIdx.x;
  if (i < NN){
    int rs = loc[i] + boff[i >> 8];
    rowstart[i] = rs; fill[i] = rs;
    dinv[i] = rsqrtf((float)cnt[i] + 1.0f);     // +1 self loop
  } else if (i == NN){
    rowstart[NN] = boff[NB1];
  }
}

__global__ void k_scatter(const int* __restrict__ ei, const int* __restrict__ ew,
                          int* __restrict__ fill, int* __restrict__ csr){
  int e = blockIdx.x*256 + threadIdx.x;
  if (e < EE && ew[e] == 1){
    int c = ei[EE + e];
    int pos = atomicAdd(&fill[c], 1);
    csr[pos] = ei[e];
  }
}

// ---------- GEMM1: Y1 = x@W1 + b1, accumulate column sum/sumsq ----------
__global__ __launch_bounds__(256) void k_gemm1(const float* __restrict__ x,
    const float* __restrict__ W1, const float* __restrict__ b1,
    float* __restrict__ Y1, float* __restrict__ stats){
  __shared__ float xs[32*132];     // 32 rows x 128, padded
  __shared__ float Ws[128*32];
  __shared__ float red[64];
  const int tid = threadIdx.x;
  for (int j = tid; j < 1024; j += 256) ((float4*)Ws)[j] = ((const float4*)W1)[j];
  const int r = tid >> 3, cg = tid & 7;
  const float4 bv = ((const float4*)b1)[cg];
  float s0=0,s1=0,s2=0,s3=0,q0=0,q1=0,q2=0,q3=0;
  for (int tile = blockIdx.x; tile < 3125; tile += gridDim.x){
    __syncthreads();
    for (int j = tid; j < 1024; j += 256){
      int rr = j >> 5, kk = j & 31;
      *(float4*)&xs[rr*132 + kk*4] = ((const float4*)x)[(size_t)tile*1024 + j];
    }
    __syncthreads();
    float a0=bv.x, a1=bv.y, a2=bv.z, a3=bv.w;
    const float* xr = &xs[r*132];
    const float* wc = &Ws[cg*4];
    #pragma unroll 8
    for (int k = 0; k < 128; k++){
      float xv = xr[k];
      float4 w = *(const float4*)&wc[k*32];
      a0 += xv*w.x; a1 += xv*w.y; a2 += xv*w.z; a3 += xv*w.w;
    }
    float4 o; o.x=a0; o.y=a1; o.z=a2; o.w=a3;
    ((float4*)Y1)[(size_t)(tile*32 + r)*8 + cg] = o;
    s0+=a0; s1+=a1; s2+=a2; s3+=a3;
    q0+=a0*a0; q1+=a1*a1; q2+=a2*a2; q3+=a3*a3;
  }
  __syncthreads();
  if (tid < 64) red[tid] = 0.f;
  __syncthreads();
  atomicAdd(&red[cg*4+0], s0); atomicAdd(&red[cg*4+1], s1);
  atomicAdd(&red[cg*4+2], s2); atomicAdd(&red[cg*4+3], s3);
  atomicAdd(&red[32+cg*4+0], q0); atomicAdd(&red[32+cg*4+1], q1);
  atomicAdd(&red[32+cg*4+2], q2); atomicAdd(&red[32+cg*4+3], q3);
  __syncthreads();
  if (tid < 64) atomicAdd(&stats[tid], red[tid]);
}

// ---------- BN finalize: scale/shift from sums ----------
__global__ void k_stats(float* __restrict__ stats, const float* __restrict__ gamma,
                        const float* __restrict__ beta, int base){
  int c = threadIdx.x;  // 32 threads
  float mean = stats[base + c] * (1.0f/NN);
  float var  = stats[base + 32 + c] * (1.0f/NN) - mean*mean;
  float sc = gamma[c] * rsqrtf(fmaxf(var, 0.0f) + BN_EPS);
  stats[base + 64 + c] = sc;
  stats[base + 96 + c] = beta[c] - mean*sc;
}

// ---------- MLP2: Y2 = relu(bn1(Y1))@W2 + b2, accumulate stats2 ----------
__global__ __launch_bounds__(256) void k_mlp2(const float* __restrict__ Y1,
    const float* __restrict__ W2, const float* __restrict__ b2,
    float* __restrict__ stats, float* __restrict__ Y2){
  __shared__ float hs[32*36];
  __shared__ float Ws[32*32];
  __shared__ float red[64];
  const int tid = threadIdx.x;
  ((float4*)Ws)[tid] = ((const float4*)W2)[tid];
  const int r = tid >> 3, cg = tid & 7;
  const float4 bv = ((const float4*)b2)[cg];
  const float4 sc = ((const float4*)(stats + 64))[cg];
  const float4 sh = ((const float4*)(stats + 96))[cg];
  float s0=0,s1=0,s2=0,s3=0,q0=0,q1=0,q2=0,q3=0;
  for (int tile = blockIdx.x; tile < 3125; tile += gridDim.x){
    __syncthreads();
    {
      float4 v = ((const float4*)Y1)[(size_t)tile*256 + tid];
      v.x = fmaxf(fmaf(v.x, sc.x, sh.x), 0.f);
      v.y = fmaxf(fmaf(v.y, sc.y, sh.y), 0.f);
      v.z = fmaxf(fmaf(v.z, sc.z, sh.z), 0.f);
      v.w = fmaxf(fmaf(v.w, sc.w, sh.w), 0.f);
      *(float4*)&hs[r*36 + cg*4] = v;
    }
    __syncthreads();
    float a0=bv.x, a1=bv.y, a2=bv.z, a3=bv.w;
    const float* hr = &hs[r*36];
    const float* wc = &Ws[cg*4];
    #pragma unroll
    for (int k = 0; k < 32; k++){
      float h = hr[k];
      float4 w = *(const float4*)&wc[k*32];
      a0 += h*w.x; a1 += h*w.y; a2 += h*w.z; a3 += h*w.w;
    }
    float4 o; o.x=a0; o.y=a1; o.z=a2; o.w=a3;
    ((float4*)Y2)[(size_t)(tile*32 + r)*8 + cg] = o;
    s0+=a0; s1+=a1; s2+=a2; s3+=a3;
    q0+=a0*a0; q1+=a1*a1; q2+=a2*a2; q3+=a3*a3;
  }
  __syncthreads();
  if (tid < 64) red[tid] = 0.f;
  __syncthreads();
  atomicAdd(&red[cg*4+0], s0); atomicAdd(&red[cg*4+1], s1);
  atomicAdd(&red[cg*4+2], s2); atomicAdd(&red[cg*4+3], s3);
  atomicAdd(&red[32+cg*4+0], q0); atomicAdd(&red[32+cg*4+1], q1);
  atomicAdd(&red[32+cg*4+2], q2); atomicAdd(&red[32+cg*4+3], q3);
  __syncthreads();
  if (tid < 64) atomicAdd(&stats[128 + tid], red[tid]);
}

// ---------- layer0: h1 = relu(bn2(Y2)); Pool0 <- max(h1@Wl0+bl0); Hg1 = h1@Wg1 ----------
__global__ __launch_bounds__(256) void k_layer0(const float* __restrict__ Y2,
    const float* __restrict__ stats, const float* __restrict__ Wg1,
    const float* __restrict__ Wl0, const float* __restrict__ bl0,
    const int* __restrict__ batch,
    float* __restrict__ Hg1, unsigned* __restrict__ Pool0){
  __shared__ float hs[32*36];
  __shared__ float Wg[32*64];
  __shared__ float Wl[320];
  __shared__ float bl[10];
  const int tid = threadIdx.x;
  ((float4*)Wg)[tid]       = ((const float4*)Wg1)[tid];
  ((float4*)Wg)[tid + 256] = ((const float4*)Wg1)[tid + 256];
  for (int j = tid; j < 320; j += 256) Wl[j] = Wl0[j];
  if (tid < 10)  bl[tid] = bl0[tid];
  {
    const int rr = tid >> 3, kk = tid & 7;
    const float4 sc = ((const float4*)(stats + 192))[kk];
    const float4 sh = ((const float4*)(stats + 224))[kk];
    float4 v = ((const float4*)Y2)[(size_t)blockIdx.x*256 + tid];
    v.x = fmaxf(fmaf(v.x, sc.x, sh.x), 0.f);
    v.y = fmaxf(fmaf(v.y, sc.y, sh.y), 0.f);
    v.z = fmaxf(fmaf(v.z, sc.z, sh.z), 0.f);
    v.w = fmaxf(fmaf(v.w, sc.w, sh.w), 0.f);
    *(float4*)&hs[rr*36 + kk*4] = v;
  }
  __syncthreads();
  const int w = tid >> 6, f = tid & 63;
  for (int i = 0; i < 8; i++){
    const int r = w*8 + i;
    const int row = blockIdx.x*32 + r;
    const float* hr = &hs[r*36];
    float acc = 0.f;
    #pragma unroll
    for (int k = 0; k < 32; k++) acc += hr[k]*Wg[k*64 + f];
    Hg1[(size_t)row*64 + f] = acc;
    if (f < 10){
      float p = bl[f];
      #pragma unroll
      for (int k = 0; k < 32; k++) p += hr[k]*Wl[k*10 + f];
      atomicMax(&Pool0[batch[row]*10 + f], encf(p));
    }
  }
}

// ---------- gather aggregation: h = (sum_in H[r]*dinv[r])*dinv[c]
//            + H[c]*dinv[c]^2 + bias; optional store; pool max ----------
template<bool STORE>
__global__ __launch_bounds__(256) void k_agg(const float* __restrict__ H,
    const float* __restrict__ dinv, const int* __restrict__ rowstart,
    const int* __restrict__ csr, const float* __restrict__ bias,
    const int* __restrict__ batch, float* __restrict__ outp,
    unsigned* __restrict__ Pool){
  const int c = blockIdx.x*4 + (threadIdx.x >> 6);
  const int f = threadIdx.x & 63;
  const int s = rowstart[c], e = rowstart[c+1];
  const float dc = dinv[c];
  float accn = 0.f;
  int j = s;
  for (; j + 1 < e; j += 2){
    int r0 = csr[j], r1 = csr[j+1];
    float d0 = dinv[r0], d1 = dinv[r1];
    accn += H[(size_t)r0*64 + f]*d0;
    accn += H[(size_t)r1*64 + f]*d1;
  }
  if (j < e){ int r = csr[j]; accn += H[(size_t)r*64 + f]*dinv[r]; }
  float h = fmaf(accn, dc, H[(size_t)c*64 + f]*dc*dc) + bias[f];
  if (STORE) outp[(size_t)c*64 + f] = h;
  atomicMax(&Pool[batch[c]*64 + f], encf(h));
}

// ---------- layer1 GEMM: Hg2 = h2 @ Wg2 ----------
__global__ __launch_bounds__(256) void k_layer1(const float* __restrict__ H2,
    const float* __restrict__ Wg2, float* __restrict__ Hg2){
  __shared__ float as[32*68];
  __shared__ float Wg[64*64];
  const int tid = threadIdx.x;
  #pragma unroll
  for (int j = 0; j < 4; j++) ((float4*)Wg)[tid + j*256] = ((const float4*)Wg2)[tid + j*256];
  #pragma unroll
  for (int j = 0; j < 2; j++){
    int idx = tid + j*256;
    int rr = idx >> 4, kk = idx & 15;
    *(float4*)&as[rr*68 + kk*4] = ((const float4*)H2)[(size_t)blockIdx.x*512 + idx];
  }
  __syncthreads();
  const int w = tid >> 6, f = tid & 63;
  for (int i = 0; i < 8; i++){
    const int r = w*8 + i;
    const float* ar = &as[r*68];
    float acc = 0.f;
    #pragma unroll
    for (int k = 0; k < 64; k++) acc += ar[k]*Wg[k*64 + f];
    Hg2[(size_t)(blockIdx.x*32 + r)*64 + f] = acc;
  }
}

// ---------- final: out = P0 + P1@Wl1+bl1 + P2@Wl2+bl2 ----------
__global__ __launch_bounds__(256) void k_final(const unsigned* __restrict__ P0,
    const unsigned* __restrict__ P1, const unsigned* __restrict__ P2,
    const float* __restrict__ Wl1, const float* __restrict__ bl1,
    const float* __restrict__ Wl2, const float* __restrict__ bl2,
    float* __restrict__ out){
  const int t = blockIdx.x*256 + threadIdx.x;
  const int g = t >> 4, c = t & 15;
  if (g >= GG || c >= 10) return;
  float acc = dec0(P0[g*10 + c]) + bl1[c] + bl2[c];
  for (int f = 0; f < 64; f++){
    acc += dec0(P1[g*64 + f]) * Wl1[f*10 + c];
    acc += dec0(P2[g*64 + f]) * Wl2[f*10 + c];
  }
  out[g*10 + c] = acc;
}

extern "C" void kernel_launch(void* const* d_in, const int* in_sizes, int n_in,
                              void* d_out, int out_size, void* d_ws, size_t ws_size,
                              hipStream_t stream){
  const float* x   = (const float*)d_in[0];
  const int*   ei  = (const int*)d_in[1];
  const int*   ew  = (const int*)d_in[2];
  const int*   bat = (const int*)d_in[3];
  const float* W1  = (const float*)d_in[5],  *b1  = (const float*)d_in[6];
  const float* g1  = (const float*)d_in[7],  *bt1 = (const float*)d_in[8];
  const float* W2  = (const float*)d_in[9],  *b2  = (const float*)d_in[10];
  const float* g2  = (const float*)d_in[11], *bt2 = (const float*)d_in[12];
  const float* Wl0 = (const float*)d_in[13], *bl0 = (const float*)d_in[14];
  const float* Wg1 = (const float*)d_in[15], *bg1 = (const float*)d_in[16];
  const float* Wl1 = (const float*)d_in[17], *bl1 = (const float*)d_in[18];
  const float* Wg2 = (const float*)d_in[19], *bg2 = (const float*)d_in[20];
  const float* Wl2 = (const float*)d_in[21], *bl2 = (const float*)d_in[22];

  float* ws = (float*)d_ws;
  // workspace layout (4B elems). Zeroed prefix: cnt | stats | P0 | P1 | P2
  const size_t oCnt   = 0;                         // NN ints
  const size_t oStats = NN;                        // 256
  const size_t oP0    = oStats + 256;              // G*10
  const size_t oP1    = oP0 + (size_t)GG*10;       // G*64
  const size_t oP2    = oP1 + (size_t)GG*64;       // G*64
  const size_t oZEnd  = oP2 + (size_t)GG*64;       // zero prefix end (238256)
  const size_t oDinv  = oZEnd;                     // NN
  const size_t oLoc   = oDinv + NN;                // NN
  const size_t oBsum  = oLoc + NN;                 // 512
  const size_t oBoff  = oBsum + 512;               // 512
  const size_t oRS    = oBoff + 512;               // NN+8
  const size_t oFill  = oRS + NN + 8;              // NN
  const size_t oCsr   = oFill + NN;                // EE
  const size_t oA     = oCsr + EE;                 // NN*64 (Y1|Y2 -> H2)
  const size_t oB     = oA + (size_t)NN*64;        // NN*64 (Hg1 -> Hg2)

  int*   cnt   = (int*)(ws + oCnt);
  float* stats = ws + oStats;
  unsigned* P0 = (unsigned*)(ws + oP0);
  unsigned* P1 = (unsigned*)(ws + oP1);
  unsigned* P2 = (unsigned*)(ws + oP2);
  float* dinv  = ws + oDinv;
  int*   loc   = (int*)(ws + oLoc);
  int*   bsum  = (int*)(ws + oBsum);
  int*   boff  = (int*)(ws + oBoff);
  int*   rs    = (int*)(ws + oRS);
  int*   fill  = (int*)(ws + oFill);
  int*   csr   = (int*)(ws + oCsr);
  float* Y1    = ws + oA;
  float* Y2    = ws + oA + (size_t)NN*32;
  float* H2    = ws + oA;      // reuse after Y1/Y2 consumed
  float* Hg1   = ws + oB;
  float* Hg2   = ws + oB;      // reuse after Hg1 consumed

  (void)hipMemsetAsync(d_ws, 0, oZEnd*sizeof(float), stream);

  // CSR build (shared by both GCN layers)
  k_count  <<<EE/256, 256, 0, stream>>>(ei, ew, cnt);
  k_scan1  <<<NB1, 256, 0, stream>>>(cnt, loc, bsum);
  k_scan2  <<<1, 512, 0, stream>>>(bsum, boff);
  k_fin    <<<NB1, 256, 0, stream>>>(cnt, loc, boff, dinv, rs, fill);
  k_scatter<<<EE/256, 256, 0, stream>>>(ei, ew, fill, csr);

  // MLP + heads
  k_gemm1<<<512, 256, 0, stream>>>(x, W1, b1, Y1, stats);
  k_stats<<<1, 32, 0, stream>>>(stats, g1, bt1, 0);
  k_mlp2 <<<512, 256, 0, stream>>>(Y1, W2, b2, stats, Y2);
  k_stats<<<1, 32, 0, stream>>>(stats, g2, bt2, 128);
  k_layer0<<<3125, 256, 0, stream>>>(Y2, stats, Wg1, Wl0, bl0, bat, Hg1, P0);
  k_agg<true> <<<NN/4, 256, 0, stream>>>(Hg1, dinv, rs, csr, bg1, bat, H2, P1);
  k_layer1<<<3125, 256, 0, stream>>>(H2, Wg2, Hg2);
  k_agg<false><<<NN/4, 256, 0, stream>>>(Hg2, dinv, rs, csr, bg2, bat, nullptr, P2);
  k_final<<<(GG*16 + 255)/256, 256, 0, stream>>>(P0, P1, P2, Wl1, bl1, Wl2, bl2, (float*)d_out);
}